// Round 14
// baseline (423.836 us; speedup 1.0000x reference)
//
#include <hip/hip_runtime.h>
#include <stdint.h>

typedef __attribute__((ext_vector_type(8))) short short8;
typedef __attribute__((ext_vector_type(4))) float f32x4;

// ---- workspace: bf16 weights in FRAGMENT-LINEAR layout ----
// fragment (nt,kt) = contiguous 1024B chunk: [(nt*NKT+kt)*64 + lane]*8 shorts.
// element e of lane = W^T[nt*16 + (lane&15)][kt*32 + ((lane>>4)<<3) + e]
#define OW1R  0        // rad_w1^T  [64][64]   NT=4  NKT=2   4096 shorts
#define OW2R  4096     // rad_w2^T  [768][64]  NT=48 NKT=2   49152
#define OW0T  53248    // lin_w0^T  [384][384] NT=24 NKT=12  147456 (scaled)
#define OW1CT 200704   // lin_w1C^T [128][256] NT=8  NKT=8   32768  (scaled)
#define OW1DT 233472   // lin_w1D^T [128][128] NT=8  NKT=4   16384  (scaled)

// ---- LDS layout (bytes), 48 KB ----
// OES [32][64] bf16 swz (ph0-1) | OHS [32][64] bf16 swz (ph2..ph3-top)
// OD0 [32][384] bf16 swz stride 768 (ph3-4); OH [32][68] f32 aliases OD0 (ph1-2)
// OZC [32][256] bf16 swz (ph3a-4b)
// OZDS single zD plane [32][128] bf16 swz, aliases OES+OHS (dead after ph3-top;
// first write is after the post-3a barrier)
#define OES   0
#define OHS   4096
#define OD0   8192
#define OH    8192
#define OZC   32768
#define OZDS  0
#define SMEM_BYTES 49152

static constexpr float C_SILU      = 1.6765390f;   // 1/sqrt(E[silu(z)^2])
static constexpr float C_SIG       = 1.8462240f;   // 1/sqrt(E[sigmoid(z)^2])
static constexpr float INV_SQRT3   = 0.5773502691896258f;
static constexpr float INV_SQRT2   = 0.7071067811865476f;
static constexpr float INV_SQRT_FAN= 0.051031036307982884f; // 1/sqrt(384)

__device__ __forceinline__ short f2bf(float f) {
  union { float f; uint32_t u; } v; v.f = f;
  uint32_t u = v.u;
  u += 0x7FFFu + ((u >> 16) & 1u);   // RNE to bf16
  return (short)(u >> 16);
}

__device__ __forceinline__ f32x4 mfma16(short8 a, short8 b, f32x4 c) {
  return __builtin_amdgcn_mfma_f32_16x16x32_bf16(a, b, c, 0, 0, 0);
}

// B fragment, fragment-linear layout: one coalesced 16B/lane load.
__device__ __forceinline__ short8 ldF(const short* __restrict__ W, int nkt, int nt, int kt, int lane) {
  return *(const short8*)(W + ((((nt * nkt) + kt) << 6) + lane) * 8);
}

// ---------- weight prep: transpose + bf16 + scale fold + fragment-linear pack ----------
__global__ void prep_weights(const float* __restrict__ rw1, const float* __restrict__ rw2,
                             const float* __restrict__ lw0, const float* __restrict__ lw1,
                             short* __restrict__ ws)
{
  int idx = blockIdx.x * blockDim.x + threadIdx.x;
  int stride = gridDim.x * blockDim.x;
  // W1R: NKT=2
  for (int i = idx; i < 4096; i += stride) {
    int e = i & 7, lane = (i >> 3) & 63, f = i >> 9;
    int kt = f & 1, nt = f >> 1;
    int n = nt * 16 + (lane & 15), k = kt * 32 + ((lane >> 4) << 3) + e;
    ws[OW1R + i] = f2bf(rw1[k * 64 + n]);
  }
  // W2R: NKT=2
  for (int i = idx; i < 49152; i += stride) {
    int e = i & 7, lane = (i >> 3) & 63, f = i >> 9;
    int kt = f & 1, nt = f >> 1;
    int n = nt * 16 + (lane & 15), k = kt * 32 + ((lane >> 4) << 3) + e;
    ws[OW2R + i] = f2bf(rw2[k * 768 + n]);
  }
  // W0T: NKT=12
  for (int i = idx; i < 147456; i += stride) {
    int e = i & 7, lane = (i >> 3) & 63, f = i >> 9;
    int kt = f % 12, nt = f / 12;
    int n = nt * 16 + (lane & 15), k = kt * 32 + ((lane >> 4) << 3) + e;
    ws[OW0T + i] = f2bf(lw0[k * 384 + n] * INV_SQRT_FAN);
  }
  // W1CT: NKT=8
  for (int i = idx; i < 32768; i += stride) {
    int e = i & 7, lane = (i >> 3) & 63, f = i >> 9;
    int kt = f & 7, nt = f >> 3;
    int n = nt * 16 + (lane & 15), k = kt * 32 + ((lane >> 4) << 3) + e;
    ws[OW1CT + i] = f2bf(lw1[k * 128 + n] * INV_SQRT_FAN);
  }
  // W1DT: NKT=4 (source offset +256)
  for (int i = idx; i < 16384; i += stride) {
    int e = i & 7, lane = (i >> 3) & 63, f = i >> 9;
    int kt = f & 3, nt = f >> 2;
    int n = nt * 16 + (lane & 15), k = kt * 32 + ((lane >> 4) << 3) + e;
    ws[OW1DT + i] = f2bf(lw1[(256 + k) * 128 + n] * INV_SQRT_FAN);
  }
}

// swizzle: row-stride multiples of 128B; spread rows 0..15 over distinct bank groups
#define SWZ(row, byte) ((byte) ^ ((((row) & 7) << 4) ^ (((row) & 8) << 2)))
#define LDA(base, c2, row, k0) \
  (*(const short8*)(smem + (base) + (row) * (c2) + SWZ(row, (k0) << 1)))
#define STBF(base, c2, row, col, val) \
  (*(short*)(smem + (base) + (row) * (c2) + SWZ(row, (col) << 1)) = f2bf(val))

// ---------- fused main kernel: 32 edges per block ----------
__global__ __launch_bounds__(256) void fctp_fused(
    const float* __restrict__ node, const float* __restrict__ eattr,
    const float* __restrict__ escal, const float* __restrict__ lng,
    const float* __restrict__ lnb, const float* __restrict__ roff,
    const float* __restrict__ b0v, const short* __restrict__ ws,
    float* __restrict__ out)
{
  __shared__ char smem[SMEM_BYTES];
  const int t = threadIdx.x;
  const int lane = t & 63;
  const int w = t >> 6;
  const int row0 = blockIdx.x << 5;
  const int l15 = lane & 15;
  const int kof = (lane >> 4) << 3;   // K-offset (elements) of this lane's A/B fragment
  const int rb0 = (lane >> 4) << 2;   // accumulator row base within 16-row tile

  // ================= prefetch (issued before any compute) =================
  const int pr = t >> 3, pc0 = (t & 7) << 3;
  const float* pesc = escal + (size_t)(row0 + pr) * 64 + pc0;
  float4 ev0 = *(const float4*)pesc;
  float4 ev1 = *(const float4*)(pesc + 4);

  float4 lg0 = *(const float4*)(lng + pc0);
  float4 lg1 = *(const float4*)(lng + pc0 + 4);
  float4 lb0 = *(const float4*)(lnb + pc0);
  float4 lb1 = *(const float4*)(lnb + pc0 + 4);

  float offAr[4], offCr[4], offBr[2], offDr[2];
#pragma unroll
  for (int j = 0; j < 4; ++j) {
    int u = (((w << 2) + j) << 4) + l15;
    offAr[j] = roff[u];
    offCr[j] = roff[256 + u];
  }
#pragma unroll
  for (int j = 0; j < 2; ++j) {
    int u = (((w << 1) + j) << 4) + l15;
    offBr[j] = roff[512 + u];
    offDr[j] = roff[640 + u];
  }

  float x0r[4][2][4];
#pragma unroll
  for (int j = 0; j < 4; ++j) {
    int u = (((w << 2) + j) << 4) + l15;
#pragma unroll
    for (int rt = 0; rt < 2; ++rt)
#pragma unroll
      for (int i = 0; i < 4; ++i)
        x0r[j][rt][i] = node[(size_t)(row0 + rt * 16 + rb0 + i) * 640 + u];
  }
  float x1r[2][2][4][3];
#pragma unroll
  for (int j = 0; j < 2; ++j) {
    int u = (((w << 1) + j) << 4) + l15;
#pragma unroll
    for (int rt = 0; rt < 2; ++rt)
#pragma unroll
      for (int i = 0; i < 4; ++i) {
        const float* xp = node + (size_t)(row0 + rt * 16 + rb0 + i) * 640 + 256 + u * 3;
        x1r[j][rt][i][0] = xp[0];
        x1r[j][rt][i][1] = xp[1];
        x1r[j][rt][i][2] = xp[2];
      }
  }

  // ---- phase 0: stage edge_scalars (bf16 swizzled) ----
  {
    short8 bv;
    bv[0] = f2bf(ev0.x); bv[1] = f2bf(ev0.y); bv[2] = f2bf(ev0.z); bv[3] = f2bf(ev0.w);
    bv[4] = f2bf(ev1.x); bv[5] = f2bf(ev1.y); bv[6] = f2bf(ev1.z); bv[7] = f2bf(ev1.w);
    *(short8*)(smem + OES + pr * 128 + SWZ(pr, pc0 << 1)) = bv;
  }
  __syncthreads();

  // ---- phase 1: h = es @ rad_w1  (G1), write f32 h to LDS ----
  {
    short8 bf0 = ldF(ws + OW1R, 2, w, 0, lane);
    short8 bf1 = ldF(ws + OW1R, 2, w, 1, lane);
    float* sh_h = (float*)(smem + OH);
    int colh = (w << 4) + l15;
#pragma unroll
    for (int rt = 0; rt < 2; ++rt) {
      int r = rt * 16 + l15;
      f32x4 acc = {0.f, 0.f, 0.f, 0.f};
      acc = mfma16(LDA(OES, 128, r, kof), bf0, acc);
      acc = mfma16(LDA(OES, 128, r, 32 + kof), bf1, acc);
      int rb = rt * 16 + rb0;
#pragma unroll
      for (int i = 0; i < 4; ++i) sh_h[(rb + i) * 68 + colh] = acc[i];
    }
  }
  __syncthreads();

  // ---- phase 2: LayerNorm + silu -> OHS (bf16 swizzled) ----
  {
    const float* sh_h = (const float*)(smem + OH);
    float vals[8]; float s = 0.f, s2 = 0.f;
#pragma unroll
    for (int j = 0; j < 8; ++j) {
      float v = sh_h[pr * 68 + pc0 + j];
      vals[j] = v; s += v; s2 += v * v;
    }
#pragma unroll
    for (int off = 1; off < 8; off <<= 1) {
      s  += __shfl_xor(s, off, 64);
      s2 += __shfl_xor(s2, off, 64);
    }
    float mu = s * 0.015625f;
    float var = s2 * 0.015625f - mu * mu;
    float rstd = rsqrtf(var + 1e-5f);
    float lg[8] = {lg0.x, lg0.y, lg0.z, lg0.w, lg1.x, lg1.y, lg1.z, lg1.w};
    float lb[8] = {lb0.x, lb0.y, lb0.z, lb0.w, lb1.x, lb1.y, lb1.z, lb1.w};
    short8 hv;
#pragma unroll
    for (int j = 0; j < 8; ++j) {
      float v = (vals[j] - mu) * rstd * lg[j] + lb[j];
      float sv = v / (1.f + __expf(-v));
      hv[j] = f2bf(sv);
    }
    *(short8*)(smem + OHS + pr * 128 + SWZ(pr, pc0 << 1)) = hv;
  }
  __syncthreads();

  // ---- phase 3 top: per-row attr (direct from global) + A-fragments of hs ----
  float s0r[2][4], sar[2][4], sbr[2][4], scr[2][4];
#pragma unroll
  for (int rt = 0; rt < 2; ++rt)
#pragma unroll
    for (int i = 0; i < 4; ++i) {
      int row = rt * 16 + rb0 + i;
      float4 att = *(const float4*)(eattr + (size_t)(row0 + row) * 4);
      s0r[rt][i] = att.x;
      sar[rt][i] = att.y;
      sbr[rt][i] = att.z;
      scr[rt][i] = att.w;
    }
  short8 a00 = LDA(OHS, 128, l15, kof);
  short8 a01 = LDA(OHS, 128, l15, 32 + kof);
  short8 a10 = LDA(OHS, 128, 16 + l15, kof);
  short8 a11 = LDA(OHS, 128, 16 + l15, 32 + kof);

  // ---- phase 3a: wA (cols 0..255) paired with wC (256..511): share x0 ----
#pragma unroll
  for (int j = 0; j < 4; ++j) {
    int ut = (w << 2) + j;
    short8 bA0 = ldF(ws + OW2R, 2, ut, 0, lane);
    short8 bA1 = ldF(ws + OW2R, 2, ut, 1, lane);
    short8 bC0 = ldF(ws + OW2R, 2, ut + 16, 0, lane);
    short8 bC1 = ldF(ws + OW2R, 2, ut + 16, 1, lane);
    int u = (ut << 4) + l15;
#pragma unroll
    for (int rt = 0; rt < 2; ++rt) {
      short8 fa = rt ? a10 : a00, fb = rt ? a11 : a01;
      f32x4 accA = {0.f,0.f,0.f,0.f}, accC = {0.f,0.f,0.f,0.f};
      accA = mfma16(fa, bA0, accA); accA = mfma16(fb, bA1, accA);
      accC = mfma16(fa, bC0, accC); accC = mfma16(fb, bC1, accC);
#pragma unroll
      for (int i = 0; i < 4; ++i) {
        int row = rt * 16 + rb0 + i;
        float x0v = x0r[j][rt][i];
        STBF(OD0, 768, row, u, x0v * s0r[rt][i] * (accA[i] + offAr[j]));
        STBF(OZC, 512, row, u, x0v * (accC[i] + offCr[j]));
      }
    }
  }
  // All waves' OES/OHS reads (phase-1 + a00..a11) are complete past this
  // barrier; the OZDS plane buffer (aliasing OES+OHS) may now be written.
  __syncthreads();

  // ---- phase 3b: wB -> d0 x1-part; wD -> zd regs + plane A (xa*zd) ----
  float zd[2][2][4];
#pragma unroll
  for (int j = 0; j < 2; ++j) {
    int ut = (w << 1) + j;
    short8 bB0 = ldF(ws + OW2R, 2, 32 + ut, 0, lane);
    short8 bB1 = ldF(ws + OW2R, 2, 32 + ut, 1, lane);
    short8 bD0 = ldF(ws + OW2R, 2, 40 + ut, 0, lane);
    short8 bD1 = ldF(ws + OW2R, 2, 40 + ut, 1, lane);
    int u = (ut << 4) + l15;
#pragma unroll
    for (int rt = 0; rt < 2; ++rt) {
      short8 fa = rt ? a10 : a00, fb = rt ? a11 : a01;
      f32x4 accB = {0.f,0.f,0.f,0.f}, accD = {0.f,0.f,0.f,0.f};
      accB = mfma16(fa, bB0, accB); accB = mfma16(fb, bB1, accB);
      accD = mfma16(fa, bD0, accD); accD = mfma16(fb, bD1, accD);
#pragma unroll
      for (int i = 0; i < 4; ++i) {
        int row = rt * 16 + rb0 + i;
        float xa = x1r[j][rt][i][0], xb = x1r[j][rt][i][1], xc = x1r[j][rt][i][2];
        float wB = accB[i] + offBr[j];
        STBF(OD0, 768, row, 256 + u,
             (xa * sar[rt][i] + xb * sbr[rt][i] + xc * scr[rt][i]) * INV_SQRT3 * wB);
        float z = (accD[i] + offDr[j]) * INV_SQRT2;
        zd[j][rt][i] = z;
        STBF(OZDS, 256, row, u, xa * z);   // plane A
      }
    }
  }
  __syncthreads();   // plane A visible

  // ---- phase 4c: p[m] = zD[m] @ W1DT, one plane at a time ----
  f32x4 pacc[3][2][2];
#pragma unroll
  for (int m = 0; m < 3; ++m)
#pragma unroll
    for (int j = 0; j < 2; ++j)
#pragma unroll
      for (int rt = 0; rt < 2; ++rt) pacc[m][j][rt] = (f32x4){0.f, 0.f, 0.f, 0.f};

#pragma unroll
  for (int m = 0; m < 3; ++m) {
    if (m > 0) {
      __syncthreads();   // previous plane's reads done; safe to overwrite
#pragma unroll
      for (int j = 0; j < 2; ++j) {
        int u = (((w << 1) + j) << 4) + l15;
#pragma unroll
        for (int rt = 0; rt < 2; ++rt)
#pragma unroll
          for (int i = 0; i < 4; ++i) {
            int row = rt * 16 + rb0 + i;
            STBF(OZDS, 256, row, u, x1r[j][rt][i][m] * zd[j][rt][i]);
          }
      }
      __syncthreads();   // plane m visible
    }
    short8 Az[2][4];
#pragma unroll
    for (int kt4 = 0; kt4 < 4; ++kt4) {
      int k0 = kt4 * 32 + kof;
      Az[0][kt4] = LDA(OZDS, 256, l15, k0);
      Az[1][kt4] = LDA(OZDS, 256, 16 + l15, k0);
    }
#pragma unroll
    for (int j = 0; j < 2; ++j) {
      int vt = (w << 1) + j;
      short8 Bfr[4];
#pragma unroll
      for (int kt4 = 0; kt4 < 4; ++kt4) Bfr[kt4] = ldF(ws + OW1DT, 4, vt, kt4, lane);
#pragma unroll
      for (int kt4 = 0; kt4 < 4; ++kt4) {
        pacc[m][j][0] = mfma16(Az[0][kt4], Bfr[kt4], pacc[m][j][0]);
        pacc[m][j][1] = mfma16(Az[1][kt4], Bfr[kt4], pacc[m][j][1]);
      }
    }
  }

  // ---- 4a: silu col-tiles in pairs; write out, release accumulators ----
#pragma unroll
  for (int cp = 0; cp < 2; ++cp) {
    f32x4 sacc[2][2];
#pragma unroll
    for (int q = 0; q < 2; ++q)
#pragma unroll
      for (int rt = 0; rt < 2; ++rt) sacc[q][rt] = (f32x4){0.f, 0.f, 0.f, 0.f};
#pragma unroll
    for (int kt = 0; kt < 12; ++kt) {
      int k0 = kt * 32 + kof;
      short8 Af0 = LDA(OD0, 768, l15, k0);
      short8 Af1 = LDA(OD0, 768, 16 + l15, k0);
      short8 Bf0 = ldF(ws + OW0T, 12, (w << 2) + 2 * cp,     kt, lane);
      short8 Bf1 = ldF(ws + OW0T, 12, (w << 2) + 2 * cp + 1, kt, lane);
      sacc[0][0] = mfma16(Af0, Bf0, sacc[0][0]);
      sacc[0][1] = mfma16(Af1, Bf0, sacc[0][1]);
      sacc[1][0] = mfma16(Af0, Bf1, sacc[1][0]);
      sacc[1][1] = mfma16(Af1, Bf1, sacc[1][1]);
    }
#pragma unroll
    for (int q = 0; q < 2; ++q) {
      int col = (((w << 2) + 2 * cp + q) << 4) + l15;
      float bias = b0v[col];
#pragma unroll
      for (int rt = 0; rt < 2; ++rt) {
#pragma unroll
        for (int i = 0; i < 4; ++i) {
          float v = sacc[q][rt][i] + bias;
          float sv = v / (1.f + __expf(-v));
          out[(size_t)(row0 + rt * 16 + rb0 + i) * 640 + col] = C_SILU * sv;
        }
      }
    }
  }

  // ---- 4a': gate col-tiles (live until final epilogue) ----
  f32x4 gacc[2][2];
#pragma unroll
  for (int j = 0; j < 2; ++j)
#pragma unroll
    for (int rt = 0; rt < 2; ++rt) gacc[j][rt] = (f32x4){0.f, 0.f, 0.f, 0.f};
#pragma unroll
  for (int kt = 0; kt < 12; ++kt) {
    int k0 = kt * 32 + kof;
    short8 Af0 = LDA(OD0, 768, l15, k0);
    short8 Af1 = LDA(OD0, 768, 16 + l15, k0);
    short8 Bg0 = ldF(ws + OW0T, 12, 16 + (w << 1),     kt, lane);
    short8 Bg1 = ldF(ws + OW0T, 12, 16 + (w << 1) + 1, kt, lane);
    gacc[0][0] = mfma16(Af0, Bg0, gacc[0][0]);
    gacc[0][1] = mfma16(Af1, Bg0, gacc[0][1]);
    gacc[1][0] = mfma16(Af0, Bg1, gacc[1][0]);
    gacc[1][1] = mfma16(Af1, Bg1, gacc[1][1]);
  }

  // ---- phase 4b: yc = zC @ W1CT ----
  f32x4 ycacc[2][2];
#pragma unroll
  for (int j = 0; j < 2; ++j)
#pragma unroll
    for (int rt = 0; rt < 2; ++rt) ycacc[j][rt] = (f32x4){0.f, 0.f, 0.f, 0.f};
  {
    short8 Az[2][8];
#pragma unroll
    for (int kt = 0; kt < 8; ++kt) {
      int k0 = kt * 32 + kof;
      Az[0][kt] = LDA(OZC, 512, l15, k0);
      Az[1][kt] = LDA(OZC, 512, 16 + l15, k0);
    }
#pragma unroll
    for (int j = 0; j < 2; ++j) {
      int vt = (w << 1) + j;
      short8 Bfr[8];
#pragma unroll
      for (int kt = 0; kt < 8; ++kt) Bfr[kt] = ldF(ws + OW1CT, 8, vt, kt, lane);
#pragma unroll
      for (int kt = 0; kt < 8; ++kt) {
        ycacc[j][0] = mfma16(Az[0][kt], Bfr[kt], ycacc[j][0]);
        ycacc[j][1] = mfma16(Az[1][kt], Bfr[kt], ycacc[j][1]);
      }
    }
  }

  // ---- final epilogue: gates + factored out1 ----
  {
#pragma unroll
    for (int j = 0; j < 2; ++j) {
      int v = (((w << 1) + j) << 4) + l15;
      float bias = b0v[256 + v];
#pragma unroll
      for (int rt = 0; rt < 2; ++rt) {
#pragma unroll
        for (int i = 0; i < 4; ++i) {
          int row = rt * 16 + rb0 + i;
          float gate = C_SIG / (1.f + __expf(-(gacc[j][rt][i] + bias)));
          float ra = sar[rt][i], rb = sbr[rt][i], rc = scr[rt][i];
          float yc = ycacc[j][rt][i];
          float q0 = pacc[0][j][rt][i], q1 = pacc[1][j][rt][i], q2 = pacc[2][j][rt][i];
          float o0 = ra * yc + (rc * q1 - rb * q2);
          float o1 = rb * yc + (ra * q2 - rc * q0);
          float o2 = rc * yc + (rb * q0 - ra * q1);
          float* op = out + (size_t)(row0 + row) * 640 + 256 + v * 3;
          op[0] = o0 * gate; op[1] = o1 * gate; op[2] = o2 * gate;
        }
      }
    }
  }
}

extern "C" void kernel_launch(void* const* d_in, const int* in_sizes, int n_in,
                              void* d_out, int out_size, void* d_ws, size_t ws_size,
                              hipStream_t stream) {
  const float* node_input   = (const float*)d_in[0];
  const float* edge_attr    = (const float*)d_in[1];
  const float* edge_scalars = (const float*)d_in[2];
  const float* rad_w1       = (const float*)d_in[3];
  const float* rad_ln_g     = (const float*)d_in[4];
  const float* rad_ln_b     = (const float*)d_in[5];
  const float* rad_w2       = (const float*)d_in[6];
  const float* rad_offset   = (const float*)d_in[7];
  const float* lin_w0       = (const float*)d_in[8];
  const float* lin_b0       = (const float*)d_in[9];
  const float* lin_w1       = (const float*)d_in[10];
  short* wsb = (short*)d_ws;
  float* out = (float*)d_out;

  prep_weights<<<256, 256, 0, stream>>>(rad_w1, rad_w2, lin_w0, lin_w1, wsb);
  fctp_fused<<<131072 / 32, 256, 0, stream>>>(node_input, edge_attr, edge_scalars,
                                              rad_ln_g, rad_ln_b, rad_offset,
                                              lin_b0, wsb, out);
}

// Round 15
// 306.215 us; speedup vs baseline: 1.3841x; 1.3841x over previous
//
#include <hip/hip_runtime.h>
#include <stdint.h>

typedef __attribute__((ext_vector_type(8))) short short8;
typedef __attribute__((ext_vector_type(4))) float f32x4;

// ---- workspace: bf16 weights in FRAGMENT-LINEAR layout ----
// fragment (nt,kt) = contiguous 1024B chunk: [(nt*NKT+kt)*64 + lane]*8 shorts.
// element e of lane = W^T[nt*16 + (lane&15)][kt*32 + ((lane>>4)<<3) + e]
#define OW1R  0        // rad_w1^T  [64][64]   NT=4  NKT=2   4096 shorts
#define OW2R  4096     // rad_w2^T  [768][64]  NT=48 NKT=2   49152
#define OW0T  53248    // lin_w0^T  [384][384] NT=24 NKT=12  147456 (scaled)
#define OW1CT 200704   // lin_w1C^T [128][256] NT=8  NKT=8   32768  (scaled)
#define OW1DT 233472   // lin_w1D^T [128][128] NT=8  NKT=4   16384  (scaled)

// ---- LDS layout (bytes) ----
#define OATTR 0        // [32][4] f32 edge_attr
#define OES   512      // [32][64] bf16, swizzled (A for G1)
#define OHS   4608     // [32][64] bf16, swizzled (A for G2)
#define OD0   8704     // [32][384] bf16, swizzled (A for out0 GEMM)
#define OH    8704     // [32][68] f32 (LN staging; overlaps OD0, dead before d0 written)
#define OZC   33280    // [32][256] bf16, swizzled
#define OZD0  49664    // [32][128] bf16, swizzled (then +8192 per m)
#define SMEM_BYTES 74240

static constexpr float C_SILU      = 1.6765390f;   // 1/sqrt(E[silu(z)^2])
static constexpr float C_SIG       = 1.8462240f;   // 1/sqrt(E[sigmoid(z)^2])
static constexpr float INV_SQRT3   = 0.5773502691896258f;
static constexpr float INV_SQRT2   = 0.7071067811865476f;
static constexpr float INV_SQRT_FAN= 0.051031036307982884f; // 1/sqrt(384)

__device__ __forceinline__ short f2bf(float f) {
  union { float f; uint32_t u; } v; v.f = f;
  uint32_t u = v.u;
  u += 0x7FFFu + ((u >> 16) & 1u);   // RNE to bf16
  return (short)(u >> 16);
}

__device__ __forceinline__ f32x4 mfma16(short8 a, short8 b, f32x4 c) {
  return __builtin_amdgcn_mfma_f32_16x16x32_bf16(a, b, c, 0, 0, 0);
}

// B fragment, fragment-linear layout: one coalesced 16B/lane load.
__device__ __forceinline__ short8 ldF(const short* __restrict__ W, int nkt, int nt, int kt, int lane) {
  return *(const short8*)(W + ((((nt * nkt) + kt) << 6) + lane) * 8);
}

// ---------- weight prep: transpose + bf16 + scale fold + fragment-linear pack ----------
__global__ void prep_weights(const float* __restrict__ rw1, const float* __restrict__ rw2,
                             const float* __restrict__ lw0, const float* __restrict__ lw1,
                             short* __restrict__ ws)
{
  int idx = blockIdx.x * blockDim.x + threadIdx.x;
  int stride = gridDim.x * blockDim.x;
  // W1R: NKT=2
  for (int i = idx; i < 4096; i += stride) {
    int e = i & 7, lane = (i >> 3) & 63, f = i >> 9;
    int kt = f & 1, nt = f >> 1;
    int n = nt * 16 + (lane & 15), k = kt * 32 + ((lane >> 4) << 3) + e;
    ws[OW1R + i] = f2bf(rw1[k * 64 + n]);
  }
  // W2R: NKT=2
  for (int i = idx; i < 49152; i += stride) {
    int e = i & 7, lane = (i >> 3) & 63, f = i >> 9;
    int kt = f & 1, nt = f >> 1;
    int n = nt * 16 + (lane & 15), k = kt * 32 + ((lane >> 4) << 3) + e;
    ws[OW2R + i] = f2bf(rw2[k * 768 + n]);
  }
  // W0T: NKT=12
  for (int i = idx; i < 147456; i += stride) {
    int e = i & 7, lane = (i >> 3) & 63, f = i >> 9;
    int kt = f % 12, nt = f / 12;
    int n = nt * 16 + (lane & 15), k = kt * 32 + ((lane >> 4) << 3) + e;
    ws[OW0T + i] = f2bf(lw0[k * 384 + n] * INV_SQRT_FAN);
  }
  // W1CT: NKT=8
  for (int i = idx; i < 32768; i += stride) {
    int e = i & 7, lane = (i >> 3) & 63, f = i >> 9;
    int kt = f & 7, nt = f >> 3;
    int n = nt * 16 + (lane & 15), k = kt * 32 + ((lane >> 4) << 3) + e;
    ws[OW1CT + i] = f2bf(lw1[k * 128 + n] * INV_SQRT_FAN);
  }
  // W1DT: NKT=4 (source offset +256)
  for (int i = idx; i < 16384; i += stride) {
    int e = i & 7, lane = (i >> 3) & 63, f = i >> 9;
    int kt = f & 3, nt = f >> 2;
    int n = nt * 16 + (lane & 15), k = kt * 32 + ((lane >> 4) << 3) + e;
    ws[OW1DT + i] = f2bf(lw1[(256 + k) * 128 + n] * INV_SQRT_FAN);
  }
}

// swizzle: row-stride multiples of 128B; spread rows 0..15 over distinct bank groups
#define SWZ(row, byte) ((byte) ^ ((((row) & 7) << 4) ^ (((row) & 8) << 2)))
#define LDA(base, c2, row, k0) \
  (*(const short8*)(smem + (base) + (row) * (c2) + SWZ(row, (k0) << 1)))
#define STBF(base, c2, row, col, val) \
  (*(short*)(smem + (base) + (row) * (c2) + SWZ(row, (col) << 1)) = f2bf(val))

// ---------- fused main kernel: 32 edges per block ----------
__global__ __launch_bounds__(256) void fctp_fused(
    const float* __restrict__ node, const float* __restrict__ eattr,
    const float* __restrict__ escal, const float* __restrict__ lng,
    const float* __restrict__ lnb, const float* __restrict__ roff,
    const float* __restrict__ b0v, const short* __restrict__ ws,
    float* __restrict__ out)
{
  __shared__ char smem[SMEM_BYTES];
  const int t = threadIdx.x;
  const int lane = t & 63;
  const int w = t >> 6;
  const int row0 = blockIdx.x << 5;
  const int l15 = lane & 15;
  const int kof = (lane >> 4) << 3;   // K-offset (elements) of this lane's A/B fragment
  const int rb0 = (lane >> 4) << 2;   // accumulator row base within 16-row tile

  // ================= prefetch (issued before any compute) =================
  float attr_v = 0.f;
  if (t < 128) attr_v = eattr[(size_t)row0 * 4 + t];
  const int pr = t >> 3, pc0 = (t & 7) << 3;
  const float* pesc = escal + (size_t)(row0 + pr) * 64 + pc0;
  float4 ev0 = *(const float4*)pesc;
  float4 ev1 = *(const float4*)(pesc + 4);

  float4 lg0 = *(const float4*)(lng + pc0);
  float4 lg1 = *(const float4*)(lng + pc0 + 4);
  float4 lb0 = *(const float4*)(lnb + pc0);
  float4 lb1 = *(const float4*)(lnb + pc0 + 4);

  float offAr[4], offCr[4], offBr[2], offDr[2];
#pragma unroll
  for (int j = 0; j < 4; ++j) {
    int u = (((w << 2) + j) << 4) + l15;
    offAr[j] = roff[u];
    offCr[j] = roff[256 + u];
  }
#pragma unroll
  for (int j = 0; j < 2; ++j) {
    int u = (((w << 1) + j) << 4) + l15;
    offBr[j] = roff[512 + u];
    offDr[j] = roff[640 + u];
  }

  float x0r[4][2][4];
#pragma unroll
  for (int j = 0; j < 4; ++j) {
    int u = (((w << 2) + j) << 4) + l15;
#pragma unroll
    for (int rt = 0; rt < 2; ++rt)
#pragma unroll
      for (int i = 0; i < 4; ++i)
        x0r[j][rt][i] = node[(size_t)(row0 + rt * 16 + rb0 + i) * 640 + u];
  }
  float x1r[2][2][4][3];
#pragma unroll
  for (int j = 0; j < 2; ++j) {
    int u = (((w << 1) + j) << 4) + l15;
#pragma unroll
    for (int rt = 0; rt < 2; ++rt)
#pragma unroll
      for (int i = 0; i < 4; ++i) {
        const float* xp = node + (size_t)(row0 + rt * 16 + rb0 + i) * 640 + 256 + u * 3;
        x1r[j][rt][i][0] = xp[0];
        x1r[j][rt][i][1] = xp[1];
        x1r[j][rt][i][2] = xp[2];
      }
  }

  // ---- phase 0: stage edge_attr (f32) and edge_scalars (bf16 swizzled) ----
  {
    if (t < 128) ((float*)(smem + OATTR))[t] = attr_v;
    short8 bv;
    bv[0] = f2bf(ev0.x); bv[1] = f2bf(ev0.y); bv[2] = f2bf(ev0.z); bv[3] = f2bf(ev0.w);
    bv[4] = f2bf(ev1.x); bv[5] = f2bf(ev1.y); bv[6] = f2bf(ev1.z); bv[7] = f2bf(ev1.w);
    *(short8*)(smem + OES + pr * 128 + SWZ(pr, pc0 << 1)) = bv;
  }
  __syncthreads();

  // ---- phase 1: h = es @ rad_w1  (G1), write f32 h to LDS ----
  {
    short8 bf0 = ldF(ws + OW1R, 2, w, 0, lane);
    short8 bf1 = ldF(ws + OW1R, 2, w, 1, lane);
    float* sh_h = (float*)(smem + OH);
    int colh = (w << 4) + l15;
#pragma unroll
    for (int rt = 0; rt < 2; ++rt) {
      int r = rt * 16 + l15;
      f32x4 acc = {0.f, 0.f, 0.f, 0.f};
      acc = mfma16(LDA(OES, 128, r, kof), bf0, acc);
      acc = mfma16(LDA(OES, 128, r, 32 + kof), bf1, acc);
      int rb = rt * 16 + rb0;
#pragma unroll
      for (int i = 0; i < 4; ++i) sh_h[(rb + i) * 68 + colh] = acc[i];
    }
  }
  __syncthreads();

  // ---- phase 2: LayerNorm + silu -> HS (bf16 swizzled) ----
  {
    const float* sh_h = (const float*)(smem + OH);
    float vals[8]; float s = 0.f, s2 = 0.f;
#pragma unroll
    for (int j = 0; j < 8; ++j) {
      float v = sh_h[pr * 68 + pc0 + j];
      vals[j] = v; s += v; s2 += v * v;
    }
#pragma unroll
    for (int off = 1; off < 8; off <<= 1) {
      s  += __shfl_xor(s, off, 64);
      s2 += __shfl_xor(s2, off, 64);
    }
    float mu = s * 0.015625f;
    float var = s2 * 0.015625f - mu * mu;
    float rstd = rsqrtf(var + 1e-5f);
    float lg[8] = {lg0.x, lg0.y, lg0.z, lg0.w, lg1.x, lg1.y, lg1.z, lg1.w};
    float lb[8] = {lb0.x, lb0.y, lb0.z, lb0.w, lb1.x, lb1.y, lb1.z, lb1.w};
    short8 hv;
#pragma unroll
    for (int j = 0; j < 8; ++j) {
      float v = (vals[j] - mu) * rstd * lg[j] + lb[j];
      float sv = v / (1.f + __expf(-v));
      hv[j] = f2bf(sv);
    }
    *(short8*)(smem + OHS + pr * 128 + SWZ(pr, pc0 << 1)) = hv;
  }
  __syncthreads();

  // ---- phase 3: w = hs @ rad_w2 (+offset) fused into d0 / zC / zD builds ----
  {
    const float* attr = (const float*)(smem + OATTR);
    float s0r[2][4], sar[2][4], sbr[2][4], scr[2][4];
#pragma unroll
    for (int rt = 0; rt < 2; ++rt)
#pragma unroll
      for (int i = 0; i < 4; ++i) {
        int row = rt * 16 + rb0 + i;
        s0r[rt][i] = attr[row * 4 + 0];
        sar[rt][i] = attr[row * 4 + 1];
        sbr[rt][i] = attr[row * 4 + 2];
        scr[rt][i] = attr[row * 4 + 3];
      }
    short8 a00 = LDA(OHS, 128, l15, kof);
    short8 a01 = LDA(OHS, 128, l15, 32 + kof);
    short8 a10 = LDA(OHS, 128, 16 + l15, kof);
    short8 a11 = LDA(OHS, 128, 16 + l15, 32 + kof);

    // wA (cols 0..255) paired with wC (256..511): share x0
#pragma unroll
    for (int j = 0; j < 4; ++j) {
      int ut = (w << 2) + j;
      short8 bA0 = ldF(ws + OW2R, 2, ut, 0, lane);
      short8 bA1 = ldF(ws + OW2R, 2, ut, 1, lane);
      short8 bC0 = ldF(ws + OW2R, 2, ut + 16, 0, lane);
      short8 bC1 = ldF(ws + OW2R, 2, ut + 16, 1, lane);
      int u = (ut << 4) + l15;
#pragma unroll
      for (int rt = 0; rt < 2; ++rt) {
        short8 fa = rt ? a10 : a00, fb = rt ? a11 : a01;
        f32x4 accA = {0.f,0.f,0.f,0.f}, accC = {0.f,0.f,0.f,0.f};
        accA = mfma16(fa, bA0, accA); accA = mfma16(fb, bA1, accA);
        accC = mfma16(fa, bC0, accC); accC = mfma16(fb, bC1, accC);
#pragma unroll
        for (int i = 0; i < 4; ++i) {
          int row = rt * 16 + rb0 + i;
          float x0v = x0r[j][rt][i];
          STBF(OD0, 768, row, u, x0v * s0r[rt][i] * (accA[i] + offAr[j]));
          STBF(OZC, 512, row, u, x0v * (accC[i] + offCr[j]));
        }
      }
    }
    // wB (512..639) paired with wD (640..767): share x1
#pragma unroll
    for (int j = 0; j < 2; ++j) {
      int ut = (w << 1) + j;
      short8 bB0 = ldF(ws + OW2R, 2, 32 + ut, 0, lane);
      short8 bB1 = ldF(ws + OW2R, 2, 32 + ut, 1, lane);
      short8 bD0 = ldF(ws + OW2R, 2, 40 + ut, 0, lane);
      short8 bD1 = ldF(ws + OW2R, 2, 40 + ut, 1, lane);
      int u = (ut << 4) + l15;
#pragma unroll
      for (int rt = 0; rt < 2; ++rt) {
        short8 fa = rt ? a10 : a00, fb = rt ? a11 : a01;
        f32x4 accB = {0.f,0.f,0.f,0.f}, accD = {0.f,0.f,0.f,0.f};
        accB = mfma16(fa, bB0, accB); accB = mfma16(fb, bB1, accB);
        accD = mfma16(fa, bD0, accD); accD = mfma16(fb, bD1, accD);
#pragma unroll
        for (int i = 0; i < 4; ++i) {
          int row = rt * 16 + rb0 + i;
          float xa = x1r[j][rt][i][0], xb = x1r[j][rt][i][1], xc = x1r[j][rt][i][2];
          float sa = sar[rt][i], sb = sbr[rt][i], sc = scr[rt][i];
          float wB = accB[i] + offBr[j], wD = accD[i] + offDr[j];
          STBF(OD0, 768, row, 256 + u,
               (xa * sa + xb * sb + xc * sc) * INV_SQRT3 * wB);
          float zd = wD * INV_SQRT2;
          STBF(OZD0,          256, row, u, xa * zd);
          STBF(OZD0 + 8192,   256, row, u, xb * zd);
          STBF(OZD0 + 16384,  256, row, u, xc * zd);
        }
      }
    }
  }
  __syncthreads();

  // ==== phase 4: code-motion-only ILP restructure of R13 ====
  // All per-accumulator MFMA chains keep kt-ascending order with identical
  // operands -> outputs bit-identical to R13; only independent chains are
  // interleaved.

  // ---- 4a: silu col-tiles in pairs; write out, release accumulators ----
#pragma unroll
  for (int cp = 0; cp < 2; ++cp) {
    f32x4 sacc[2][2];
#pragma unroll
    for (int q = 0; q < 2; ++q)
#pragma unroll
      for (int rt = 0; rt < 2; ++rt) sacc[q][rt] = (f32x4){0.f, 0.f, 0.f, 0.f};
#pragma unroll
    for (int kt = 0; kt < 12; ++kt) {
      int k0 = kt * 32 + kof;
      short8 Af0 = LDA(OD0, 768, l15, k0);
      short8 Af1 = LDA(OD0, 768, 16 + l15, k0);
      short8 Bf0 = ldF(ws + OW0T, 12, (w << 2) + 2 * cp,     kt, lane);
      short8 Bf1 = ldF(ws + OW0T, 12, (w << 2) + 2 * cp + 1, kt, lane);
      sacc[0][0] = mfma16(Af0, Bf0, sacc[0][0]);
      sacc[0][1] = mfma16(Af1, Bf0, sacc[0][1]);
      sacc[1][0] = mfma16(Af0, Bf1, sacc[1][0]);
      sacc[1][1] = mfma16(Af1, Bf1, sacc[1][1]);
    }
#pragma unroll
    for (int q = 0; q < 2; ++q) {
      int col = (((w << 2) + 2 * cp + q) << 4) + l15;
      float bias = b0v[col];
#pragma unroll
      for (int rt = 0; rt < 2; ++rt) {
#pragma unroll
        for (int i = 0; i < 4; ++i) {
          float v = sacc[q][rt][i] + bias;
          float sv = v / (1.f + __expf(-v));
          out[(size_t)(row0 + rt * 16 + rb0 + i) * 640 + col] = C_SILU * sv;
        }
      }
    }
  }

  // ---- merged 4a' + 4b: gates (OD0 x W0T) interleaved with yc (OZC x W1CT) ----
  f32x4 gacc[2][2], ycacc[2][2];
#pragma unroll
  for (int j = 0; j < 2; ++j)
#pragma unroll
    for (int rt = 0; rt < 2; ++rt) {
      gacc[j][rt]  = (f32x4){0.f, 0.f, 0.f, 0.f};
      ycacc[j][rt] = (f32x4){0.f, 0.f, 0.f, 0.f};
    }
#pragma unroll
  for (int kt = 0; kt < 12; ++kt) {
    int k0 = kt * 32 + kof;
    short8 Af0 = LDA(OD0, 768, l15, k0);
    short8 Af1 = LDA(OD0, 768, 16 + l15, k0);
    short8 Bg0 = ldF(ws + OW0T, 12, 16 + (w << 1),     kt, lane);
    short8 Bg1 = ldF(ws + OW0T, 12, 16 + (w << 1) + 1, kt, lane);
    gacc[0][0] = mfma16(Af0, Bg0, gacc[0][0]);
    gacc[0][1] = mfma16(Af1, Bg0, gacc[0][1]);
    gacc[1][0] = mfma16(Af0, Bg1, gacc[1][0]);
    gacc[1][1] = mfma16(Af1, Bg1, gacc[1][1]);
    if (kt < 8) {
      short8 Az0 = LDA(OZC, 512, l15, k0);
      short8 Az1 = LDA(OZC, 512, 16 + l15, k0);
      short8 Bc0 = ldF(ws + OW1CT, 8, (w << 1),     kt, lane);
      short8 Bc1 = ldF(ws + OW1CT, 8, (w << 1) + 1, kt, lane);
      ycacc[0][0] = mfma16(Az0, Bc0, ycacc[0][0]);
      ycacc[0][1] = mfma16(Az1, Bc0, ycacc[0][1]);
      ycacc[1][0] = mfma16(Az0, Bc1, ycacc[1][0]);
      ycacc[1][1] = mfma16(Az1, Bc1, ycacc[1][1]);
    }
  }

  // ---- 4c: pd planes merged into one kt4-outer loop (B-fragments hoisted) ----
  f32x4 pacc[3][2][2];
#pragma unroll
  for (int m = 0; m < 3; ++m)
#pragma unroll
    for (int j = 0; j < 2; ++j)
#pragma unroll
      for (int rt = 0; rt < 2; ++rt) pacc[m][j][rt] = (f32x4){0.f, 0.f, 0.f, 0.f};
#pragma unroll
  for (int kt4 = 0; kt4 < 4; ++kt4) {
    int k0 = kt4 * 32 + kof;
    short8 Bd0 = ldF(ws + OW1DT, 4, (w << 1),     kt4, lane);
    short8 Bd1 = ldF(ws + OW1DT, 4, (w << 1) + 1, kt4, lane);
#pragma unroll
    for (int m = 0; m < 3; ++m) {
      short8 A0 = LDA(OZD0 + m * 8192, 256, l15, k0);
      short8 A1 = LDA(OZD0 + m * 8192, 256, 16 + l15, k0);
      pacc[m][0][0] = mfma16(A0, Bd0, pacc[m][0][0]);
      pacc[m][0][1] = mfma16(A1, Bd0, pacc[m][0][1]);
      pacc[m][1][0] = mfma16(A0, Bd1, pacc[m][1][0]);
      pacc[m][1][1] = mfma16(A1, Bd1, pacc[m][1][1]);
    }
  }

  // ---- final epilogue: gates + factored out1 ----
  {
    const float* attr = (const float*)(smem + OATTR);
#pragma unroll
    for (int j = 0; j < 2; ++j) {
      int v = (((w << 1) + j) << 4) + l15;
      float bias = b0v[256 + v];
#pragma unroll
      for (int rt = 0; rt < 2; ++rt) {
#pragma unroll
        for (int i = 0; i < 4; ++i) {
          int row = rt * 16 + rb0 + i;
          float gate = C_SIG / (1.f + __expf(-(gacc[j][rt][i] + bias)));
          float ra = attr[row * 4 + 1], rb = attr[row * 4 + 2], rc = attr[row * 4 + 3];
          float yc = ycacc[j][rt][i];
          float q0 = pacc[0][j][rt][i], q1 = pacc[1][j][rt][i], q2 = pacc[2][j][rt][i];
          float o0 = ra * yc + (rc * q1 - rb * q2);
          float o1 = rb * yc + (ra * q2 - rc * q0);
          float o2 = rc * yc + (rb * q0 - ra * q1);
          float* op = out + (size_t)(row0 + row) * 640 + 256 + v * 3;
          op[0] = o0 * gate; op[1] = o1 * gate; op[2] = o2 * gate;
        }
      }
    }
  }
}

extern "C" void kernel_launch(void* const* d_in, const int* in_sizes, int n_in,
                              void* d_out, int out_size, void* d_ws, size_t ws_size,
                              hipStream_t stream) {
  const float* node_input   = (const float*)d_in[0];
  const float* edge_attr    = (const float*)d_in[1];
  const float* edge_scalars = (const float*)d_in[2];
  const float* rad_w1       = (const float*)d_in[3];
  const float* rad_ln_g     = (const float*)d_in[4];
  const float* rad_ln_b     = (const float*)d_in[5];
  const float* rad_w2       = (const float*)d_in[6];
  const float* rad_offset   = (const float*)d_in[7];
  const float* lin_w0       = (const float*)d_in[8];
  const float* lin_b0       = (const float*)d_in[9];
  const float* lin_w1       = (const float*)d_in[10];
  short* wsb = (short*)d_ws;
  float* out = (float*)d_out;

  prep_weights<<<256, 256, 0, stream>>>(rad_w1, rad_w2, lin_w0, lin_w1, wsb);
  fctp_fused<<<131072 / 32, 256, 0, stream>>>(node_input, edge_attr, edge_scalars,
                                              rad_ln_g, rad_ln_b, rad_offset,
                                              lin_b0, wsb, out);
}

// Round 16
// 297.096 us; speedup vs baseline: 1.4266x; 1.0307x over previous
//
#include <hip/hip_runtime.h>
#include <stdint.h>

typedef __attribute__((ext_vector_type(8))) short short8;
typedef __attribute__((ext_vector_type(4))) float f32x4;
typedef __attribute__((ext_vector_type(8))) float float8;

// ---- workspace: bf16 weights in FRAGMENT-LINEAR layout ----
// fragment (nt,kt) = contiguous 1024B chunk: [(nt*NKT+kt)*64 + lane]*8 shorts.
// element e of lane = W^T[nt*16 + (lane&15)][kt*32 + ((lane>>4)<<3) + e]
#define OW1R  0        // rad_w1^T  [64][64]   NT=4  NKT=2   4096 shorts
#define OW2R  4096     // rad_w2^T  [768][64]  NT=48 NKT=2   49152
#define OW0T  53248    // lin_w0^T  [384][384] NT=24 NKT=12  147456 (scaled)
#define OW1CT 200704   // lin_w1C^T [128][256] NT=8  NKT=8   32768  (scaled)
#define OW1DT 233472   // lin_w1D^T [128][128] NT=8  NKT=4   16384  (scaled)

// ---- LDS layout (bytes) ---- (OATTR/OES regions retained but unused)
#define OATTR 0
#define OES   512
#define OHS   4608     // [32][64] bf16, swizzled (A for G2)
#define OD0   8704     // [32][384] bf16, swizzled (A for out0 GEMM)
#define OH    8704     // [32][68] f32 (LN staging; overlaps OD0, dead before d0 written)
#define OZC   33280    // [32][256] bf16, swizzled
#define OZD0  49664    // [32][128] bf16, swizzled (then +8192 per m)
#define SMEM_BYTES 74240

static constexpr float C_SILU      = 1.6765390f;   // 1/sqrt(E[silu(z)^2])
static constexpr float C_SIG       = 1.8462240f;   // 1/sqrt(E[sigmoid(z)^2])
static constexpr float INV_SQRT3   = 0.5773502691896258f;
static constexpr float INV_SQRT2   = 0.7071067811865476f;
static constexpr float INV_SQRT_FAN= 0.051031036307982884f; // 1/sqrt(384)

__device__ __forceinline__ short f2bf(float f) {
  union { float f; uint32_t u; } v; v.f = f;
  uint32_t u = v.u;
  u += 0x7FFFu + ((u >> 16) & 1u);   // RNE to bf16
  return (short)(u >> 16);
}

__device__ __forceinline__ f32x4 mfma16(short8 a, short8 b, f32x4 c) {
  return __builtin_amdgcn_mfma_f32_16x16x32_bf16(a, b, c, 0, 0, 0);
}

// B fragment, fragment-linear layout: one coalesced 16B/lane load.
__device__ __forceinline__ short8 ldF(const short* __restrict__ W, int nkt, int nt, int kt, int lane) {
  return *(const short8*)(W + ((((nt * nkt) + kt) << 6) + lane) * 8);
}

// ---------- weight prep: transpose + bf16 + scale fold + fragment-linear pack ----------
__global__ void prep_weights(const float* __restrict__ rw1, const float* __restrict__ rw2,
                             const float* __restrict__ lw0, const float* __restrict__ lw1,
                             short* __restrict__ ws)
{
  int idx = blockIdx.x * blockDim.x + threadIdx.x;
  int stride = gridDim.x * blockDim.x;
  // W1R: NKT=2
  for (int i = idx; i < 4096; i += stride) {
    int e = i & 7, lane = (i >> 3) & 63, f = i >> 9;
    int kt = f & 1, nt = f >> 1;
    int n = nt * 16 + (lane & 15), k = kt * 32 + ((lane >> 4) << 3) + e;
    ws[OW1R + i] = f2bf(rw1[k * 64 + n]);
  }
  // W2R: NKT=2
  for (int i = idx; i < 49152; i += stride) {
    int e = i & 7, lane = (i >> 3) & 63, f = i >> 9;
    int kt = f & 1, nt = f >> 1;
    int n = nt * 16 + (lane & 15), k = kt * 32 + ((lane >> 4) << 3) + e;
    ws[OW2R + i] = f2bf(rw2[k * 768 + n]);
  }
  // W0T: NKT=12
  for (int i = idx; i < 147456; i += stride) {
    int e = i & 7, lane = (i >> 3) & 63, f = i >> 9;
    int kt = f % 12, nt = f / 12;
    int n = nt * 16 + (lane & 15), k = kt * 32 + ((lane >> 4) << 3) + e;
    ws[OW0T + i] = f2bf(lw0[k * 384 + n] * INV_SQRT_FAN);
  }
  // W1CT: NKT=8
  for (int i = idx; i < 32768; i += stride) {
    int e = i & 7, lane = (i >> 3) & 63, f = i >> 9;
    int kt = f & 7, nt = f >> 3;
    int n = nt * 16 + (lane & 15), k = kt * 32 + ((lane >> 4) << 3) + e;
    ws[OW1CT + i] = f2bf(lw1[k * 128 + n] * INV_SQRT_FAN);
  }
  // W1DT: NKT=4 (source offset +256)
  for (int i = idx; i < 16384; i += stride) {
    int e = i & 7, lane = (i >> 3) & 63, f = i >> 9;
    int kt = f & 3, nt = f >> 2;
    int n = nt * 16 + (lane & 15), k = kt * 32 + ((lane >> 4) << 3) + e;
    ws[OW1DT + i] = f2bf(lw1[(256 + k) * 128 + n] * INV_SQRT_FAN);
  }
}

// swizzle: row-stride multiples of 128B; spread rows 0..15 over distinct bank groups
#define SWZ(row, byte) ((byte) ^ ((((row) & 7) << 4) ^ (((row) & 8) << 2)))
#define LDA(base, c2, row, k0) \
  (*(const short8*)(smem + (base) + (row) * (c2) + SWZ(row, (k0) << 1)))
#define STBF(base, c2, row, col, val) \
  (*(short*)(smem + (base) + (row) * (c2) + SWZ(row, (col) << 1)) = f2bf(val))

// ---------- fused main kernel: 32 edges per block ----------
__global__ __launch_bounds__(256) void fctp_fused(
    const float* __restrict__ node, const float* __restrict__ eattr,
    const float* __restrict__ escal, const float* __restrict__ lng,
    const float* __restrict__ lnb, const float* __restrict__ roff,
    const float* __restrict__ b0v, const short* __restrict__ ws,
    float* __restrict__ out)
{
  __shared__ char smem[SMEM_BYTES];
  const int t = threadIdx.x;
  const int lane = t & 63;
  const int w = t >> 6;
  const int row0 = blockIdx.x << 5;
  const int l15 = lane & 15;
  const int kof = (lane >> 4) << 3;   // K-offset (elements) of this lane's A/B fragment
  const int rb0 = (lane >> 4) << 2;   // accumulator row base within 16-row tile

  // ================= prefetch (issued before any compute) =================
  const int pr = t >> 3, pc0 = (t & 7) << 3;

  float4 lg0 = *(const float4*)(lng + pc0);
  float4 lg1 = *(const float4*)(lng + pc0 + 4);
  float4 lb0 = *(const float4*)(lnb + pc0);
  float4 lb1 = *(const float4*)(lnb + pc0 + 4);

  float offAr[4], offCr[4], offBr[2], offDr[2];
#pragma unroll
  for (int j = 0; j < 4; ++j) {
    int u = (((w << 2) + j) << 4) + l15;
    offAr[j] = roff[u];
    offCr[j] = roff[256 + u];
  }
#pragma unroll
  for (int j = 0; j < 2; ++j) {
    int u = (((w << 1) + j) << 4) + l15;
    offBr[j] = roff[512 + u];
    offDr[j] = roff[640 + u];
  }

  // per-row edge_attr scalars, direct from global (R11-validated; values
  // identical to the LDS-staged copy R13 used)
  float s0r[2][4], sar[2][4], sbr[2][4], scr[2][4];
#pragma unroll
  for (int rt = 0; rt < 2; ++rt)
#pragma unroll
    for (int i = 0; i < 4; ++i) {
      int row = rt * 16 + rb0 + i;
      float4 att = *(const float4*)(eattr + (size_t)(row0 + row) * 4);
      s0r[rt][i] = att.x;
      sar[rt][i] = att.y;
      sbr[rt][i] = att.z;
      scr[rt][i] = att.w;
    }

  float x0r[4][2][4];
#pragma unroll
  for (int j = 0; j < 4; ++j) {
    int u = (((w << 2) + j) << 4) + l15;
#pragma unroll
    for (int rt = 0; rt < 2; ++rt)
#pragma unroll
      for (int i = 0; i < 4; ++i)
        x0r[j][rt][i] = node[(size_t)(row0 + rt * 16 + rb0 + i) * 640 + u];
  }
  float x1r[2][2][4][3];
#pragma unroll
  for (int j = 0; j < 2; ++j) {
    int u = (((w << 1) + j) << 4) + l15;
#pragma unroll
    for (int rt = 0; rt < 2; ++rt)
#pragma unroll
      for (int i = 0; i < 4; ++i) {
        const float* xp = node + (size_t)(row0 + rt * 16 + rb0 + i) * 640 + 256 + u * 3;
        x1r[j][rt][i][0] = xp[0];
        x1r[j][rt][i][1] = xp[1];
        x1r[j][rt][i][2] = xp[2];
      }
  }

  // ---- phase 1: h = es @ rad_w1 (G1); A-fragments built directly from
  // global escal (same floats -> same f2bf bf16 as the old staged path) ----
  {
    short8 bf0 = ldF(ws + OW1R, 2, w, 0, lane);
    short8 bf1 = ldF(ws + OW1R, 2, w, 1, lane);
    float* sh_h = (float*)(smem + OH);
    int colh = (w << 4) + l15;
#pragma unroll
    for (int rt = 0; rt < 2; ++rt) {
      int r = rt * 16 + l15;
      const float* ep = escal + (size_t)(row0 + r) * 64;
      float8 e0 = *(const float8*)(ep + kof);
      float8 e1 = *(const float8*)(ep + 32 + kof);
      short8 ae0, ae1;
#pragma unroll
      for (int jj = 0; jj < 8; ++jj) { ae0[jj] = f2bf(e0[jj]); ae1[jj] = f2bf(e1[jj]); }
      f32x4 acc = {0.f, 0.f, 0.f, 0.f};
      acc = mfma16(ae0, bf0, acc);
      acc = mfma16(ae1, bf1, acc);
      int rb = rt * 16 + rb0;
#pragma unroll
      for (int i = 0; i < 4; ++i) sh_h[(rb + i) * 68 + colh] = acc[i];
    }
  }
  __syncthreads();

  // ---- phase 2: LayerNorm + silu -> HS (bf16 swizzled) ----
  {
    const float* sh_h = (const float*)(smem + OH);
    float vals[8]; float s = 0.f, s2 = 0.f;
#pragma unroll
    for (int j = 0; j < 8; ++j) {
      float v = sh_h[pr * 68 + pc0 + j];
      vals[j] = v; s += v; s2 += v * v;
    }
#pragma unroll
    for (int off = 1; off < 8; off <<= 1) {
      s  += __shfl_xor(s, off, 64);
      s2 += __shfl_xor(s2, off, 64);
    }
    float mu = s * 0.015625f;
    float var = s2 * 0.015625f - mu * mu;
    float rstd = rsqrtf(var + 1e-5f);
    float lg[8] = {lg0.x, lg0.y, lg0.z, lg0.w, lg1.x, lg1.y, lg1.z, lg1.w};
    float lb[8] = {lb0.x, lb0.y, lb0.z, lb0.w, lb1.x, lb1.y, lb1.z, lb1.w};
    short8 hv;
#pragma unroll
    for (int j = 0; j < 8; ++j) {
      float v = (vals[j] - mu) * rstd * lg[j] + lb[j];
      float sv = v / (1.f + __expf(-v));
      hv[j] = f2bf(sv);
    }
    *(short8*)(smem + OHS + pr * 128 + SWZ(pr, pc0 << 1)) = hv;
  }
  __syncthreads();

  // ---- phase 3: w = hs @ rad_w2 (+offset) fused into d0 / zC / zD builds ----
  {
    short8 a00 = LDA(OHS, 128, l15, kof);
    short8 a01 = LDA(OHS, 128, l15, 32 + kof);
    short8 a10 = LDA(OHS, 128, 16 + l15, kof);
    short8 a11 = LDA(OHS, 128, 16 + l15, 32 + kof);

    // wA (cols 0..255) paired with wC (256..511): share x0
#pragma unroll
    for (int j = 0; j < 4; ++j) {
      int ut = (w << 2) + j;
      short8 bA0 = ldF(ws + OW2R, 2, ut, 0, lane);
      short8 bA1 = ldF(ws + OW2R, 2, ut, 1, lane);
      short8 bC0 = ldF(ws + OW2R, 2, ut + 16, 0, lane);
      short8 bC1 = ldF(ws + OW2R, 2, ut + 16, 1, lane);
      int u = (ut << 4) + l15;
#pragma unroll
      for (int rt = 0; rt < 2; ++rt) {
        short8 fa = rt ? a10 : a00, fb = rt ? a11 : a01;
        f32x4 accA = {0.f,0.f,0.f,0.f}, accC = {0.f,0.f,0.f,0.f};
        accA = mfma16(fa, bA0, accA); accA = mfma16(fb, bA1, accA);
        accC = mfma16(fa, bC0, accC); accC = mfma16(fb, bC1, accC);
#pragma unroll
        for (int i = 0; i < 4; ++i) {
          int row = rt * 16 + rb0 + i;
          float x0v = x0r[j][rt][i];
          STBF(OD0, 768, row, u, x0v * s0r[rt][i] * (accA[i] + offAr[j]));
          STBF(OZC, 512, row, u, x0v * (accC[i] + offCr[j]));
        }
      }
    }
    // wB (512..639) paired with wD (640..767): share x1
#pragma unroll
    for (int j = 0; j < 2; ++j) {
      int ut = (w << 1) + j;
      short8 bB0 = ldF(ws + OW2R, 2, 32 + ut, 0, lane);
      short8 bB1 = ldF(ws + OW2R, 2, 32 + ut, 1, lane);
      short8 bD0 = ldF(ws + OW2R, 2, 40 + ut, 0, lane);
      short8 bD1 = ldF(ws + OW2R, 2, 40 + ut, 1, lane);
      int u = (ut << 4) + l15;
#pragma unroll
      for (int rt = 0; rt < 2; ++rt) {
        short8 fa = rt ? a10 : a00, fb = rt ? a11 : a01;
        f32x4 accB = {0.f,0.f,0.f,0.f}, accD = {0.f,0.f,0.f,0.f};
        accB = mfma16(fa, bB0, accB); accB = mfma16(fb, bB1, accB);
        accD = mfma16(fa, bD0, accD); accD = mfma16(fb, bD1, accD);
#pragma unroll
        for (int i = 0; i < 4; ++i) {
          int row = rt * 16 + rb0 + i;
          float xa = x1r[j][rt][i][0], xb = x1r[j][rt][i][1], xc = x1r[j][rt][i][2];
          float sa = sar[rt][i], sb = sbr[rt][i], sc = scr[rt][i];
          float wB = accB[i] + offBr[j], wD = accD[i] + offDr[j];
          STBF(OD0, 768, row, 256 + u,
               (xa * sa + xb * sb + xc * sc) * INV_SQRT3 * wB);
          float zd = wD * INV_SQRT2;
          STBF(OZD0,          256, row, u, xa * zd);
          STBF(OZD0 + 8192,   256, row, u, xb * zd);
          STBF(OZD0 + 16384,  256, row, u, xc * zd);
        }
      }
    }
  }
  __syncthreads();

  // ==== phase 4 (R13 structure: minimal live accumulators) ====

  // ---- 4a: silu col-tiles in pairs; write out, release accumulators ----
#pragma unroll
  for (int cp = 0; cp < 2; ++cp) {
    f32x4 sacc[2][2];
#pragma unroll
    for (int q = 0; q < 2; ++q)
#pragma unroll
      for (int rt = 0; rt < 2; ++rt) sacc[q][rt] = (f32x4){0.f, 0.f, 0.f, 0.f};
#pragma unroll
    for (int kt = 0; kt < 12; ++kt) {
      int k0 = kt * 32 + kof;
      short8 Af0 = LDA(OD0, 768, l15, k0);
      short8 Af1 = LDA(OD0, 768, 16 + l15, k0);
      short8 Bf0 = ldF(ws + OW0T, 12, (w << 2) + 2 * cp,     kt, lane);
      short8 Bf1 = ldF(ws + OW0T, 12, (w << 2) + 2 * cp + 1, kt, lane);
      sacc[0][0] = mfma16(Af0, Bf0, sacc[0][0]);
      sacc[0][1] = mfma16(Af1, Bf0, sacc[0][1]);
      sacc[1][0] = mfma16(Af0, Bf1, sacc[1][0]);
      sacc[1][1] = mfma16(Af1, Bf1, sacc[1][1]);
    }
#pragma unroll
    for (int q = 0; q < 2; ++q) {
      int col = (((w << 2) + 2 * cp + q) << 4) + l15;
      float bias = b0v[col];
#pragma unroll
      for (int rt = 0; rt < 2; ++rt) {
#pragma unroll
        for (int i = 0; i < 4; ++i) {
          float v = sacc[q][rt][i] + bias;
          float sv = v / (1.f + __expf(-v));
          out[(size_t)(row0 + rt * 16 + rb0 + i) * 640 + col] = C_SILU * sv;
        }
      }
    }
  }

  // ---- 4a': gate col-tiles (live until final epilogue) ----
  f32x4 gacc[2][2];
#pragma unroll
  for (int j = 0; j < 2; ++j)
#pragma unroll
    for (int rt = 0; rt < 2; ++rt) gacc[j][rt] = (f32x4){0.f, 0.f, 0.f, 0.f};
#pragma unroll
  for (int kt = 0; kt < 12; ++kt) {
    int k0 = kt * 32 + kof;
    short8 Af0 = LDA(OD0, 768, l15, k0);
    short8 Af1 = LDA(OD0, 768, 16 + l15, k0);
    short8 Bg0 = ldF(ws + OW0T, 12, 16 + (w << 1),     kt, lane);
    short8 Bg1 = ldF(ws + OW0T, 12, 16 + (w << 1) + 1, kt, lane);
    gacc[0][0] = mfma16(Af0, Bg0, gacc[0][0]);
    gacc[0][1] = mfma16(Af1, Bg0, gacc[0][1]);
    gacc[1][0] = mfma16(Af0, Bg1, gacc[1][0]);
    gacc[1][1] = mfma16(Af1, Bg1, gacc[1][1]);
  }

  // ---- phase 4b: yc = zC @ W1CT ----
  f32x4 ycacc[2][2];
#pragma unroll
  for (int j = 0; j < 2; ++j)
#pragma unroll
    for (int rt = 0; rt < 2; ++rt) ycacc[j][rt] = (f32x4){0.f, 0.f, 0.f, 0.f};
  {
    short8 Az[2][8];
#pragma unroll
    for (int kt = 0; kt < 8; ++kt) {
      int k0 = kt * 32 + kof;
      Az[0][kt] = LDA(OZC, 512, l15, k0);
      Az[1][kt] = LDA(OZC, 512, 16 + l15, k0);
    }
#pragma unroll
    for (int j = 0; j < 2; ++j) {
      int vt = (w << 1) + j;
      short8 Bfr[8];
#pragma unroll
      for (int kt = 0; kt < 8; ++kt) Bfr[kt] = ldF(ws + OW1CT, 8, vt, kt, lane);
#pragma unroll
      for (int kt = 0; kt < 8; ++kt) {
        ycacc[j][0] = mfma16(Az[0][kt], Bfr[kt], ycacc[j][0]);
        ycacc[j][1] = mfma16(Az[1][kt], Bfr[kt], ycacc[j][1]);
      }
    }
  }

  // ---- phase 4c: p[m] = zD[m] @ W1DT ----
  f32x4 pacc[3][2][2];
#pragma unroll
  for (int m = 0; m < 3; ++m)
#pragma unroll
    for (int j = 0; j < 2; ++j)
#pragma unroll
      for (int rt = 0; rt < 2; ++rt) pacc[m][j][rt] = (f32x4){0.f, 0.f, 0.f, 0.f};
#pragma unroll
  for (int m = 0; m < 3; ++m) {
    short8 Az[2][4];
#pragma unroll
    for (int kt4 = 0; kt4 < 4; ++kt4) {
      int k0 = kt4 * 32 + kof;
      Az[0][kt4] = LDA(OZD0 + m * 8192, 256, l15, k0);
      Az[1][kt4] = LDA(OZD0 + m * 8192, 256, 16 + l15, k0);
    }
#pragma unroll
    for (int j = 0; j < 2; ++j) {
      int vt = (w << 1) + j;
      short8 Bfr[4];
#pragma unroll
      for (int kt4 = 0; kt4 < 4; ++kt4) Bfr[kt4] = ldF(ws + OW1DT, 4, vt, kt4, lane);
#pragma unroll
      for (int kt4 = 0; kt4 < 4; ++kt4) {
        pacc[m][j][0] = mfma16(Az[0][kt4], Bfr[kt4], pacc[m][j][0]);
        pacc[m][j][1] = mfma16(Az[1][kt4], Bfr[kt4], pacc[m][j][1]);
      }
    }
  }

  // ---- final epilogue: gates + factored out1 ----
  {
#pragma unroll
    for (int j = 0; j < 2; ++j) {
      int v = (((w << 1) + j) << 4) + l15;
      float bias = b0v[256 + v];
#pragma unroll
      for (int rt = 0; rt < 2; ++rt) {
#pragma unroll
        for (int i = 0; i < 4; ++i) {
          int row = rt * 16 + rb0 + i;
          float gate = C_SIG / (1.f + __expf(-(gacc[j][rt][i] + bias)));
          float ra = sar[rt][i], rb = sbr[rt][i], rc = scr[rt][i];
          float yc = ycacc[j][rt][i];
          float q0 = pacc[0][j][rt][i], q1 = pacc[1][j][rt][i], q2 = pacc[2][j][rt][i];
          float o0 = ra * yc + (rc * q1 - rb * q2);
          float o1 = rb * yc + (ra * q2 - rc * q0);
          float o2 = rc * yc + (rb * q0 - ra * q1);
          float* op = out + (size_t)(row0 + row) * 640 + 256 + v * 3;
          op[0] = o0 * gate; op[1] = o1 * gate; op[2] = o2 * gate;
        }
      }
    }
  }
}

extern "C" void kernel_launch(void* const* d_in, const int* in_sizes, int n_in,
                              void* d_out, int out_size, void* d_ws, size_t ws_size,
                              hipStream_t stream) {
  const float* node_input   = (const float*)d_in[0];
  const float* edge_attr    = (const float*)d_in[1];
  const float* edge_scalars = (const float*)d_in[2];
  const float* rad_w1       = (const float*)d_in[3];
  const float* rad_ln_g     = (const float*)d_in[4];
  const float* rad_ln_b     = (const float*)d_in[5];
  const float* rad_w2       = (const float*)d_in[6];
  const float* rad_offset   = (const float*)d_in[7];
  const float* lin_w0       = (const float*)d_in[8];
  const float* lin_b0       = (const float*)d_in[9];
  const float* lin_w1       = (const float*)d_in[10];
  short* wsb = (short*)d_ws;
  float* out = (float*)d_out;

  prep_weights<<<256, 256, 0, stream>>>(rad_w1, rad_w2, lin_w0, lin_w1, wsb);
  fctp_fused<<<131072 / 32, 256, 0, stream>>>(node_input, edge_attr, edge_scalars,
                                              rad_ln_g, rad_ln_b, rad_offset,
                                              lin_b0, wsb, out);
}